// Round 6
// baseline (253.903 us; speedup 1.0000x reference)
//
#include <hip/hip_runtime.h>
#include <math.h>

#define BB 8
#define SS 1024
#define DD 512
#define FF 2048
#define NH 8
#define MM (BB * SS)     // 8192 rows
#define LDQKV 1536       // QKV buffer row stride (Q|K|V concatenated)

using bf8 = __attribute__((ext_vector_type(8))) short;   // 8 x bf16 (4 VGPR)
using f4  = __attribute__((ext_vector_type(4))) float;   // MFMA accumulator

#define AS1 __attribute__((address_space(1)))
#define AS3 __attribute__((address_space(3)))

__device__ __forceinline__ void gload16(const void* g, void* l) {
  // async global->LDS, 16B per lane; LDS dest = wave-uniform base + lane*16
  __builtin_amdgcn_global_load_lds((AS1 const void*)g, (AS3 void*)l, 16, 0, 0);
}

template <int N> __device__ __forceinline__ void wait_vm() {
  if constexpr (N == 0)      asm volatile("s_waitcnt vmcnt(0)" ::: "memory");
  else if constexpr (N == 5) asm volatile("s_waitcnt vmcnt(5)" ::: "memory");
  else if constexpr (N == 8) asm volatile("s_waitcnt vmcnt(8)" ::: "memory");
  else                       asm volatile("s_waitcnt vmcnt(16)" ::: "memory");
  __builtin_amdgcn_sched_barrier(0);
}

__device__ __forceinline__ void bar() {
  __builtin_amdgcn_sched_barrier(0);
  __builtin_amdgcn_s_barrier();
  __builtin_amdgcn_sched_barrier(0);
}

__device__ __forceinline__ unsigned short f2b(float f) {  // fp32 -> bf16 RNE
  union { float f; unsigned u; } v; v.f = f;
  unsigned r = v.u + 0x7fffu + ((v.u >> 16) & 1u);
  return (unsigned short)(r >> 16);
}

// gelu exact via A&S 7.1.26 erf approx (|eps| <= 1.5e-7)
__device__ __forceinline__ float gelu_f(float x) {
  float ax = fabsf(x) * 0.70710678118654752f;
  float t = 1.0f / (1.0f + 0.3275911f * ax);
  float poly = t * (0.254829592f +
               t * (-0.284496736f +
               t * (1.421413741f +
               t * (-1.453152027f + t * 1.061405429f))));
  float erfv = 1.0f - poly * __expf(-ax * ax);
  erfv = copysignf(erfv, x);
  return 0.5f * x * (1.0f + erfv);
}

// ---------------------------------------------------------------------------
// LayerNorm fp32 -> bf16. One wave per row of 512. grid = MM/4, block = 256.
// ---------------------------------------------------------------------------
__global__ __launch_bounds__(256) void ln_bf16(const float* __restrict__ x,
                                               const float* __restrict__ g,
                                               const float* __restrict__ bta,
                                               unsigned short* __restrict__ out) {
  int wave = threadIdx.x >> 6, lane = threadIdx.x & 63;
  int row = (blockIdx.x << 2) + wave;
  const float* xr = x + (size_t)row * DD;
  int base = lane << 3;
  float4 v0 = *(const float4*)(xr + base);
  float4 v1 = *(const float4*)(xr + base + 4);
  float s  = v0.x + v0.y + v0.z + v0.w + v1.x + v1.y + v1.z + v1.w;
  float sq = v0.x*v0.x + v0.y*v0.y + v0.z*v0.z + v0.w*v0.w
           + v1.x*v1.x + v1.y*v1.y + v1.z*v1.z + v1.w*v1.w;
  for (int m = 32; m; m >>= 1) { s += __shfl_xor(s, m); sq += __shfl_xor(sq, m); }
  float mu  = s * (1.0f / DD);
  float var = sq * (1.0f / DD) - mu * mu;
  float rs  = rsqrtf(var + 1e-5f);
  float xv[8], go[8], bo[8];
  *(float4*)(xv) = v0; *(float4*)(xv + 4) = v1;
  *(float4*)(go)     = *(const float4*)(g + base);
  *(float4*)(go + 4) = *(const float4*)(g + base + 4);
  *(float4*)(bo)     = *(const float4*)(bta + base);
  *(float4*)(bo + 4) = *(const float4*)(bta + base + 4);
  union { unsigned short u[8]; uint4 v; } ov;
#pragma unroll
  for (int i = 0; i < 8; i++) ov.u[i] = f2b((xv[i] - mu) * rs * go[i] + bo[i]);
  *(uint4*)(out + (size_t)row * DD + base) = ov.v;
}

// ---------------------------------------------------------------------------
// Transpose + fp32->bf16: in [K][N] fp32 -> out [N][K] bf16. grid(N/32, K/32).
// ---------------------------------------------------------------------------
__global__ __launch_bounds__(256) void tconv(const float* __restrict__ in,
                                             unsigned short* __restrict__ outp,
                                             int K, int N) {
  __shared__ float tile[32][33];
  int n0 = blockIdx.x << 5, k0 = blockIdx.y << 5;
  int c = threadIdx.x & 31, r = threadIdx.x >> 5;  // r = 0..7
#pragma unroll
  for (int i = 0; i < 4; i++)
    tile[r + 8 * i][c] = in[(size_t)(k0 + r + 8 * i) * N + n0 + c];
  __syncthreads();
#pragma unroll
  for (int i = 0; i < 4; i++)
    outp[(size_t)(n0 + r + 8 * i) * K + k0 + c] = f2b(tile[c][r + 8 * i]);
}

// fused 4x 512x512 transpose+convert; blockIdx.z selects the weight
__global__ __launch_bounds__(256) void tconv4(
    const float* __restrict__ s0, const float* __restrict__ s1,
    const float* __restrict__ s2, const float* __restrict__ s3,
    unsigned short* __restrict__ d0, unsigned short* __restrict__ d1,
    unsigned short* __restrict__ d2, unsigned short* __restrict__ d3) {
  __shared__ float tile[32][33];
  const float* in; unsigned short* outp;
  switch (blockIdx.z) {
    case 0: in = s0; outp = d0; break;
    case 1: in = s1; outp = d1; break;
    case 2: in = s2; outp = d2; break;
    default: in = s3; outp = d3; break;
  }
  int n0 = blockIdx.x << 5, k0 = blockIdx.y << 5;
  int c = threadIdx.x & 31, r = threadIdx.x >> 5;
#pragma unroll
  for (int i = 0; i < 4; i++)
    tile[r + 8 * i][c] = in[(size_t)(k0 + r + 8 * i) * DD + n0 + c];
  __syncthreads();
#pragma unroll
  for (int i = 0; i < 4; i++)
    outp[(size_t)(n0 + r + 8 * i) * DD + k0 + c] = f2b(tile[c][r + 8 * i]);
}

// ---------------------------------------------------------------------------
// bf16 MFMA GEMM, 8 waves (512 thr), big tiles: C[M,N]=epi(A[M,K]@Bt[N,K]^T)
// BK=64 (128B LDS rows, 8 x 16B slots), double-buffered, counted-vmcnt
// depth-2 prefetch (proven race-free r4/r5). Waves 2M x 4N:
//   wave tile = (BM/2) x (BN/4); FLOP/LDS-byte = WM*WN/(WM+WN).
// Swizzle: LDS[row][slot] holds global slot (slot ^ (row&7)); staging source
// pre-permuted, read XORs again (rule #21, involution; <=2-way conflicts).
// Epilogue: non-swapped C-mapping, 16-lane row-contiguous stores (clean HBM
// writebacks, 33.6MB measured in r3/4). MINW: launch_bounds waves/EU (VGPR cap).
// ---------------------------------------------------------------------------
template <int BM, int BN, int ACT, int MINW>
__global__ __launch_bounds__(512, MINW) void gemm8(
    const unsigned short* __restrict__ A,   // [M][K] bf16
    const unsigned short* __restrict__ Bt,  // [N][K] bf16
    const float* __restrict__ bias,         // [N] or null
    const float* __restrict__ res,          // [M][N] fp32 or null
    float* __restrict__ Cf,                 // fp32 out (or null)
    unsigned short* __restrict__ Cb,        // bf16 out (or null)
    int M, int N, int K, int gx) {
  constexpr int WM = BM / 2, WN = BN / 4;
  constexpr int FM = WM / 16, FN = WN / 16;
  constexpr int ACH = BM / 8;                  // A 1KB chunks (8 rows x 128B)
  constexpr int CPW = (BM + BN) / 64;          // chunks per wave per K-step
  __shared__ unsigned short As[2][BM * 64];
  __shared__ unsigned short Bs[2][BN * 64];
  int tid = threadIdx.x, wid = tid >> 6, lane = tid & 63;

  // XCD-bijective swizzle (grid % 8 == 0)
  int bid = blockIdx.x;
  int cpx = (int)gridDim.x >> 3;
  int swz = (bid & 7) * cpx + (bid >> 3);
  int m0 = (swz / gx) * BM, n0 = (swz % gx) * BN;

  int wm = (wid >> 2) * WM, wn = (wid & 3) * WN;
  int r4 = lane & 15, ksl = lane >> 4;
  int srow = lane >> 3;                    // row within 8-row chunk
  int gs = (lane & 7) ^ srow;              // inverse-swizzled 16B slot

  f4 acc[FM][FN];
#pragma unroll
  for (int i = 0; i < FM; i++)
#pragma unroll
    for (int j = 0; j < FN; j++) acc[i][j] = (f4){0.f, 0.f, 0.f, 0.f};

  auto STAGE = [&](int buf, int t) {
    int k0 = t << 6;
#pragma unroll
    for (int i = 0; i < CPW; i++) {
      int c = wid * CPW + i;
      const unsigned short* src;
      unsigned short* dst;
      if (c < ACH) {
        src = A + (size_t)(m0 + c * 8 + srow) * K + k0 + gs * 8;
        dst = &As[buf][c * 512];
      } else {
        int c2 = c - ACH;
        src = Bt + (size_t)(n0 + c2 * 8 + srow) * K + k0 + gs * 8;
        dst = &Bs[buf][c2 * 512];
      }
      gload16(src, dst);
    }
  };

  auto COMPUTE = [&](int buf) {
    __builtin_amdgcn_s_setprio(1);
#pragma unroll
    for (int k2 = 0; k2 < 2; k2++) {
      int slot = (k2 << 2) | ksl;
      bf8 af[FM], bfr[FN];
#pragma unroll
      for (int mi = 0; mi < FM; mi++) {
        int r = wm + mi * 16 + r4;
        af[mi] = *(const bf8*)((const char*)&As[buf][0] + r * 128 +
                               ((slot ^ (r & 7)) << 4));
      }
#pragma unroll
      for (int ni = 0; ni < FN; ni++) {
        int r = wn + ni * 16 + r4;
        bfr[ni] = *(const bf8*)((const char*)&Bs[buf][0] + r * 128 +
                                ((slot ^ (r & 7)) << 4));
      }
#pragma unroll
      for (int mi = 0; mi < FM; mi++)
#pragma unroll
        for (int ni = 0; ni < FN; ni++)
          acc[mi][ni] = __builtin_amdgcn_mfma_f32_16x16x32_bf16(
              af[mi], bfr[ni], acc[mi][ni], 0, 0, 0);
    }
    __builtin_amdgcn_s_setprio(0);
  };

  int nt = K >> 6;
  STAGE(0, 0);
  STAGE(1, 1);
  for (int t = 0; t < nt; t++) {
    if (t + 1 < nt) wait_vm<CPW>();  // tile t landed; tile t+1 in flight
    else            wait_vm<0>();
    bar();
    COMPUTE(t & 1);
    bar();                           // all waves done reading buf[t&1]
    if (t + 2 < nt) STAGE(t & 1, t + 2);
  }

  // epilogue: C row = m0+wm+mi*16+rq+j, col = 16 consecutive lanes (r4)
  int rq = (lane >> 4) << 2;
#pragma unroll
  for (int ni = 0; ni < FN; ni++) {
    int col = n0 + wn + ni * 16 + r4;
    float bv = bias ? bias[col] : 0.0f;
#pragma unroll
    for (int mi = 0; mi < FM; mi++) {
#pragma unroll
      for (int j = 0; j < 4; j++) {
        int row = m0 + wm + mi * 16 + rq + j;
        float v = acc[mi][ni][j] + bv;
        if (ACT) v = gelu_f(v);
        if (res) v += res[(size_t)row * N + col];
        if (Cf) Cf[(size_t)row * N + col] = v;
        else    Cb[(size_t)row * N + col] = f2b(v);
      }
    }
  }
}

// ---------------------------------------------------------------------------
// Flash attention, bf16 MFMA. grid (S/64, NH, B), block 256 (4 waves).
// Wave w owns q-rows w*16..w*16+15 of the 64-row Q tile.
// All LDS tiles are 64 rows x 64 bf16 (128B rows, 8 slots), slot^=(row&7).
// ---------------------------------------------------------------------------
__global__ __launch_bounds__(256) void attn_mfma(
    const unsigned short* __restrict__ QKV,  // [B*S][1536]
    const int* __restrict__ vlen,
    unsigned short* __restrict__ AO) {       // [B*S][512]
  __shared__ unsigned short Qs[64 * 64];
  __shared__ unsigned short Ks[64 * 64];
  __shared__ unsigned short Vt[64 * 64];     // transposed: [d][k]
  __shared__ unsigned short Ps[64 * 64];     // [q][k]
  int b = blockIdx.z, h = blockIdx.y, q0 = blockIdx.x << 6;
  int tid = threadIdx.x, wid = tid >> 6, lane = tid & 63;
  int vl = vlen[b];
  int r4 = lane & 15, ksl = lane >> 4;

  // ---- stage Q (2 chunks of 1KB per wave; chunk = 8 rows of 128B)
  int srow = lane >> 3;                 // 0..7
  int gs = (lane & 7) ^ srow;           // inverse-swizzled 16B slot
  {
    const unsigned short* qsrc =
        QKV + (size_t)(b * SS + q0 + wid * 16 + srow) * LDQKV + h * 64 + gs * 8;
    gload16(qsrc, Qs + wid * 1024);
    gload16(qsrc + (size_t)8 * LDQKV, Qs + wid * 1024 + 512);
  }
  const unsigned short* kbase =
      QKV + (size_t)(b * SS + wid * 16 + srow) * LDQKV + DD + h * 64 + gs * 8;
  int vp = tid & 31, vdg = (tid >> 5) << 3;
  const unsigned short* vbase =
      QKV + (size_t)(b * SS + 2 * vp) * LDQKV + 2 * DD + h * 64 + vdg;

  f4 o[4];
#pragma unroll
  for (int i = 0; i < 4; i++) o[i] = (f4){0.f, 0.f, 0.f, 0.f};
  float mrun[4], lrun[4];
#pragma unroll
  for (int j = 0; j < 4; j++) { mrun[j] = -3e38f; lrun[j] = 0.0f; }

  int ntiles = (vl + 63) >> 6;
  if (ntiles > 16) ntiles = 16;

  for (int t = 0; t < ntiles; t++) {
    int kg0 = t << 6;
    // stage K via global_load_lds
    const unsigned short* ks = kbase + (size_t)kg0 * LDQKV;
    gload16(ks, Ks + wid * 1024);
    gload16(ks + (size_t)8 * LDQKV, Ks + wid * 1024 + 512);
    // stage V transposed: pack key-pairs into u32, swizzled ds_write_b32
    {
      const unsigned short* v0 = vbase + (size_t)kg0 * LDQKV;
      const unsigned short* v1 = v0 + LDQKV;
      unsigned short va[8], vb[8];
      *(uint4*)va = *(const uint4*)v0;
      *(uint4*)vb = *(const uint4*)v1;
#pragma unroll
      for (int i = 0; i < 8; i++) {
        int d = vdg + i;
        unsigned val = (unsigned)va[i] | ((unsigned)vb[i] << 16);
        int byte = (d << 7) + (((vp >> 2) ^ (d & 7)) << 4) + ((vp & 3) << 2);
        *(unsigned*)((char*)Vt + byte) = val;
      }
    }
    __syncthreads();

    // ---- S = Q @ K^T  (rows: this wave's 16 q; cols: 64 keys)
    f4 s[4];
#pragma unroll
    for (int i = 0; i < 4; i++) s[i] = (f4){0.f, 0.f, 0.f, 0.f};
#pragma unroll
    for (int k2 = 0; k2 < 2; k2++) {
      int slot = (k2 << 2) + ksl;
      int qr = (wid << 4) + r4;
      bf8 aq = *(const bf8*)((const char*)Qs + (qr << 7) + ((slot ^ (qr & 7)) << 4));
#pragma unroll
      for (int ni = 0; ni < 4; ni++) {
        int kr = (ni << 4) + r4;
        bf8 bk = *(const bf8*)((const char*)Ks + (kr << 7) + ((slot ^ (kr & 7)) << 4));
        s[ni] = __builtin_amdgcn_mfma_f32_16x16x32_bf16(aq, bk, s[ni], 0, 0, 0);
      }
    }

    // ---- online softmax (rows in-register; 16-lane shfl reduce)
#pragma unroll
    for (int j = 0; j < 4; j++) {
      int qr = (wid << 4) + ((lane >> 4) << 2) + j;
      float sv[4], mx = -3e38f;
#pragma unroll
      for (int ni = 0; ni < 4; ni++) {
        float v = s[ni][j] * 0.125f;                       // 1/sqrt(64)
        if (kg0 + (ni << 4) + r4 >= vl) v = -1e6f;         // masked_softmax
        sv[ni] = v;
        mx = fmaxf(mx, v);
      }
#pragma unroll
      for (int m2 = 1; m2 < 16; m2 <<= 1) mx = fmaxf(mx, __shfl_xor(mx, m2));
      float mnew = fmaxf(mrun[j], mx);
      float al = __expf(mrun[j] - mnew);
      float ls = 0.0f;
      unsigned short pb[4];
#pragma unroll
      for (int ni = 0; ni < 4; ni++) {
        float p = __expf(sv[ni] - mnew);
        ls += p;
        pb[ni] = f2b(p);
      }
#pragma unroll
      for (int m2 = 1; m2 < 16; m2 <<= 1) ls += __shfl_xor(ls, m2);
      lrun[j] = lrun[j] * al + ls;
      mrun[j] = mnew;
#pragma unroll
      for (int ni = 0; ni < 4; ni++) {
        int kc = (ni << 4) + r4;
        int byte = (qr << 7) + (((kc >> 3) ^ (qr & 7)) << 4) + ((kc & 7) << 1);
        *(unsigned short*)((char*)Ps + byte) = pb[ni];
        o[ni][j] *= al;
      }
    }

    // ---- O += P @ V   (A = P rows of this wave; B cols = d via Vt)
#pragma unroll
    for (int k2 = 0; k2 < 2; k2++) {
      int slot = (k2 << 2) + ksl;
      int qr = (wid << 4) + r4;
      bf8 ap = *(const bf8*)((const char*)Ps + (qr << 7) + ((slot ^ (qr & 7)) << 4));
#pragma unroll
      for (int ni = 0; ni < 4; ni++) {
        int dr = (ni << 4) + r4;
        bf8 bv = *(const bf8*)((const char*)Vt + (dr << 7) + ((slot ^ (dr & 7)) << 4));
        o[ni] = __builtin_amdgcn_mfma_f32_16x16x32_bf16(ap, bv, o[ni], 0, 0, 0);
      }
    }
    __syncthreads();  // before next tile overwrites Ks/Vt
  }

  float inv[4];
#pragma unroll
  for (int j = 0; j < 4; j++) inv[j] = 1.0f / lrun[j];
#pragma unroll
  for (int ni = 0; ni < 4; ni++) {
#pragma unroll
    for (int j = 0; j < 4; j++) {
      int qr = (wid << 4) + ((lane >> 4) << 2) + j;
      int d = (ni << 4) + r4;
      AO[(size_t)(b * SS + q0 + qr) * DD + h * 64 + d] = f2b(o[ni][j] * inv[j]);
    }
  }
}

// ---------------------------------------------------------------------------
extern "C" void kernel_launch(void* const* d_in, const int* in_sizes, int n_in,
                              void* d_out, int out_size, void* d_ws,
                              size_t ws_size, hipStream_t stream) {
  const float* X    = (const float*)d_in[0];
  const int*   vln  = (const int*)d_in[1];
  const float* ln1g = (const float*)d_in[2];
  const float* ln1b = (const float*)d_in[3];
  const float* Wq   = (const float*)d_in[4];
  const float* Wk   = (const float*)d_in[5];
  const float* Wv   = (const float*)d_in[6];
  const float* Wo   = (const float*)d_in[7];
  const float* ln2g = (const float*)d_in[8];
  const float* ln2b = (const float*)d_in[9];
  const float* W1   = (const float*)d_in[10];
  const float* b1   = (const float*)d_in[11];
  const float* W2   = (const float*)d_in[12];
  const float* b2   = (const float*)d_in[13];
  float* out = (float*)d_out;

  unsigned short* ws = (unsigned short*)d_ws;
  unsigned short* h     = ws;                          // 8192x512
  unsigned short* QKVb  = h     + (size_t)MM * DD;     // 8192x1536
  unsigned short* AOb   = QKVb  + (size_t)MM * LDQKV;  // 8192x512
  unsigned short* mid   = AOb   + (size_t)MM * DD;     // 8192x2048
  unsigned short* Wqkvt = mid   + (size_t)MM * FF;     // 1536x512
  unsigned short* Wot   = Wqkvt + (size_t)3 * DD * DD; // 512x512
  unsigned short* W1t   = Wot   + (size_t)DD * DD;     // 2048x512
  unsigned short* W2t   = W1t   + (size_t)FF * DD;     // 512x2048

  dim3 blk(256);
  dim3 blk8(512);

  // weight prep: transpose + convert to bf16 [N][K]
  tconv4<<<dim3(16, 16, 4), blk, 0, stream>>>(
      Wq, Wk, Wv, Wo, Wqkvt, Wqkvt + (size_t)DD * DD,
      Wqkvt + (size_t)2 * DD * DD, Wot);
  tconv<<<dim3(64, 16), blk, 0, stream>>>(W1, W1t, DD, FF);
  tconv<<<dim3(16, 64), blk, 0, stream>>>(W2, W2t, FF, DD);

  // 1. h = bf16(LN1(X))
  ln_bf16<<<dim3(MM / 4), blk, 0, stream>>>(X, ln1g, ln1b, h);
  // 2. QKV = h @ [Wq|Wk|Wv]  (bf16 out)  [256x256, 192 blocks]
  gemm8<256, 256, 0, 2><<<dim3((LDQKV / 256) * (MM / 256)), blk8, 0, stream>>>(
      h, Wqkvt, nullptr, nullptr, nullptr, QKVb, MM, LDQKV, DD, LDQKV / 256);
  // 3. attention
  attn_mfma<<<dim3(SS / 64, NH, BB), blk, 0, stream>>>(QKVb, vln, AOb);
  // 4. out = X + AO @ Wo   (fp32)  [64x256, 256 blocks, 2/CU]
  gemm8<64, 256, 0, 4><<<dim3((DD / 256) * (MM / 64)), blk8, 0, stream>>>(
      AOb, Wot, nullptr, X, out, nullptr, MM, DD, DD, DD / 256);
  // 5. h2 = bf16(LN2(out))  (overlays h)
  ln_bf16<<<dim3(MM / 4), blk, 0, stream>>>(out, ln2g, ln2b, h);
  // 6. mid = bf16(gelu(h2 @ W1 + b1))  [256x256, 256 blocks]
  gemm8<256, 256, 1, 2><<<dim3((FF / 256) * (MM / 256)), blk8, 0, stream>>>(
      h, W1t, b1, nullptr, nullptr, mid, MM, FF, DD, FF / 256);
  // 7. out = out + mid @ W2 + b2  (fp32, in-place residual)  [64x256, 256 blk]
  gemm8<64, 256, 0, 4><<<dim3((DD / 256) * (MM / 64)), blk8, 0, stream>>>(
      mid, W2t, b2, out, out, nullptr, MM, DD, FF, DD / 256);
}

// Round 7
// 180.268 us; speedup vs baseline: 1.4085x; 1.4085x over previous
//
#include <hip/hip_runtime.h>
#include <math.h>

#define BB 8
#define SS 1024
#define DD 512
#define FF 2048
#define NH 8
#define MM (BB * SS)     // 8192 rows
#define LDQKV 1536       // QKV buffer row stride (Q|K|V concatenated)

using bf8 = __attribute__((ext_vector_type(8))) short;   // 8 x bf16 (4 VGPR)
using f4  = __attribute__((ext_vector_type(4))) float;   // MFMA accumulator

#define AS1 __attribute__((address_space(1)))
#define AS3 __attribute__((address_space(3)))

__device__ __forceinline__ void gload16(const void* g, void* l) {
  // async global->LDS, 16B per lane; LDS dest = wave-uniform base + lane*16
  __builtin_amdgcn_global_load_lds((AS1 const void*)g, (AS3 void*)l, 16, 0, 0);
}

template <int N> __device__ __forceinline__ void wait_vm() {
  if constexpr (N == 0)      asm volatile("s_waitcnt vmcnt(0)" ::: "memory");
  else if constexpr (N == 3) asm volatile("s_waitcnt vmcnt(3)" ::: "memory");
  else if constexpr (N == 4) asm volatile("s_waitcnt vmcnt(4)" ::: "memory");
  else                       asm volatile("s_waitcnt vmcnt(8)" ::: "memory");
  __builtin_amdgcn_sched_barrier(0);
}

__device__ __forceinline__ void bar() {
  __builtin_amdgcn_sched_barrier(0);
  __builtin_amdgcn_s_barrier();
  __builtin_amdgcn_sched_barrier(0);
}

__device__ __forceinline__ void lgk0() {
  asm volatile("s_waitcnt lgkmcnt(0)" ::: "memory");
  __builtin_amdgcn_sched_barrier(0);
}

__device__ __forceinline__ unsigned short f2b(float f) {  // fp32 -> bf16 RNE
  union { float f; unsigned u; } v; v.f = f;
  unsigned r = v.u + 0x7fffu + ((v.u >> 16) & 1u);
  return (unsigned short)(r >> 16);
}

// gelu exact via A&S 7.1.26 erf approx (|eps| <= 1.5e-7)
__device__ __forceinline__ float gelu_f(float x) {
  float ax = fabsf(x) * 0.70710678118654752f;
  float t = 1.0f / (1.0f + 0.3275911f * ax);
  float poly = t * (0.254829592f +
               t * (-0.284496736f +
               t * (1.421413741f +
               t * (-1.453152027f + t * 1.061405429f))));
  float erfv = 1.0f - poly * __expf(-ax * ax);
  erfv = copysignf(erfv, x);
  return 0.5f * x * (1.0f + erfv);
}

// ---------------------------------------------------------------------------
// LayerNorm fp32 -> bf16. One wave per row of 512. grid = MM/4, block = 256.
// ---------------------------------------------------------------------------
__global__ __launch_bounds__(256) void ln_bf16(const float* __restrict__ x,
                                               const float* __restrict__ g,
                                               const float* __restrict__ bta,
                                               unsigned short* __restrict__ out) {
  int wave = threadIdx.x >> 6, lane = threadIdx.x & 63;
  int row = (blockIdx.x << 2) + wave;
  const float* xr = x + (size_t)row * DD;
  int base = lane << 3;
  float4 v0 = *(const float4*)(xr + base);
  float4 v1 = *(const float4*)(xr + base + 4);
  float s  = v0.x + v0.y + v0.z + v0.w + v1.x + v1.y + v1.z + v1.w;
  float sq = v0.x*v0.x + v0.y*v0.y + v0.z*v0.z + v0.w*v0.w
           + v1.x*v1.x + v1.y*v1.y + v1.z*v1.z + v1.w*v1.w;
  for (int m = 32; m; m >>= 1) { s += __shfl_xor(s, m); sq += __shfl_xor(sq, m); }
  float mu  = s * (1.0f / DD);
  float var = sq * (1.0f / DD) - mu * mu;
  float rs  = rsqrtf(var + 1e-5f);
  float xv[8], go[8], bo[8];
  *(float4*)(xv) = v0; *(float4*)(xv + 4) = v1;
  *(float4*)(go)     = *(const float4*)(g + base);
  *(float4*)(go + 4) = *(const float4*)(g + base + 4);
  *(float4*)(bo)     = *(const float4*)(bta + base);
  *(float4*)(bo + 4) = *(const float4*)(bta + base + 4);
  union { unsigned short u[8]; uint4 v; } ov;
#pragma unroll
  for (int i = 0; i < 8; i++) ov.u[i] = f2b((xv[i] - mu) * rs * go[i] + bo[i]);
  *(uint4*)(out + (size_t)row * DD + base) = ov.v;
}

// ---------------------------------------------------------------------------
// Transpose + fp32->bf16: in [K][N] fp32 -> out [N][K] bf16. grid(N/32, K/32).
// ---------------------------------------------------------------------------
__global__ __launch_bounds__(256) void tconv(const float* __restrict__ in,
                                             unsigned short* __restrict__ outp,
                                             int K, int N) {
  __shared__ float tile[32][33];
  int n0 = blockIdx.x << 5, k0 = blockIdx.y << 5;
  int c = threadIdx.x & 31, r = threadIdx.x >> 5;  // r = 0..7
#pragma unroll
  for (int i = 0; i < 4; i++)
    tile[r + 8 * i][c] = in[(size_t)(k0 + r + 8 * i) * N + n0 + c];
  __syncthreads();
#pragma unroll
  for (int i = 0; i < 4; i++)
    outp[(size_t)(n0 + r + 8 * i) * K + k0 + c] = f2b(tile[c][r + 8 * i]);
}

// fused 4x 512x512 transpose+convert; blockIdx.z selects the weight
__global__ __launch_bounds__(256) void tconv4(
    const float* __restrict__ s0, const float* __restrict__ s1,
    const float* __restrict__ s2, const float* __restrict__ s3,
    unsigned short* __restrict__ d0, unsigned short* __restrict__ d1,
    unsigned short* __restrict__ d2, unsigned short* __restrict__ d3) {
  __shared__ float tile[32][33];
  const float* in; unsigned short* outp;
  switch (blockIdx.z) {
    case 0: in = s0; outp = d0; break;
    case 1: in = s1; outp = d1; break;
    case 2: in = s2; outp = d2; break;
    default: in = s3; outp = d3; break;
  }
  int n0 = blockIdx.x << 5, k0 = blockIdx.y << 5;
  int c = threadIdx.x & 31, r = threadIdx.x >> 5;
#pragma unroll
  for (int i = 0; i < 4; i++)
    tile[r + 8 * i][c] = in[(size_t)(k0 + r + 8 * i) * DD + n0 + c];
  __syncthreads();
#pragma unroll
  for (int i = 0; i < 4; i++)
    outp[(size_t)(n0 + r + 8 * i) * DD + k0 + c] = f2b(tile[c][r + 8 * i]);
}

// ---------------------------------------------------------------------------
// 8-phase 256x256 bf16 MFMA GEMM (m201-template port): C = epi(A @ Bt^T), bf16 out.
// BK=64, 8 waves 2Mx4N (wave tile 128x64), LDS 128 KB:
//   As/Bs[2 buf][2 half][128 rows x 64 cols]; half-tile = 16 KB = 2 gload/thread.
// Per K-tile T: 4 phases (C-quadrants x K=64), each:
//   {ds_read frags (12/4/8/0 b128) | stage 1 half-tile | bar | lgkmcnt(0) |
//    setprio(1) 16 MFMA setprio(0) | bar}
// Stage schedule (targets die one phase earlier; availability gap >= 4 phases):
//   q0: A0(T+1), q1: A1(T+1), q2: B0(T+2), q3: B1(T+2)
// vmcnt(4) once per K-tile (before next tile's q0 reads), never 0 in-loop.
// Swizzle: LDS slot = gslot ^ (row&7); source pre-permuted (involution, r3/r4).
// ---------------------------------------------------------------------------
#define MQ256(g, g2)                                                         \
  do {                                                                       \
    __builtin_amdgcn_s_setprio(1);                                           \
    _Pragma("unroll") for (int mi = 0; mi < 4; mi++)                         \
      _Pragma("unroll") for (int u = 0; u < 2; u++)                          \
        _Pragma("unroll") for (int k2 = 0; k2 < 2; k2++)                     \
          acc[(g) * 4 + mi][(g2) * 2 + u] =                                  \
              __builtin_amdgcn_mfma_f32_16x16x32_bf16(                       \
                  af[mi][k2], bfr[(g2) * 2 + u][k2],                         \
                  acc[(g) * 4 + mi][(g2) * 2 + u], 0, 0, 0);                 \
    __builtin_amdgcn_s_setprio(0);                                           \
  } while (0)

#define LB256(g2, buf)                                                       \
  do {                                                                       \
    _Pragma("unroll") for (int u = 0; u < 2; u++) {                          \
      int r = rb + ((g2) * 2 + u) * 16 + r4;                                 \
      _Pragma("unroll") for (int k2 = 0; k2 < 2; k2++)                       \
        bfr[(g2) * 2 + u][k2] = *(const bf8*)((const char*)Bs[buf][hb] +     \
            r * 128 + ((((k2 << 2) | ksl) ^ (r & 7)) << 4));                 \
    }                                                                        \
  } while (0)

template <int ACT>
__global__ __launch_bounds__(512, 1) void gemm256(
    const unsigned short* __restrict__ A,   // [M][K] bf16
    const unsigned short* __restrict__ Bt,  // [N][K] bf16
    const float* __restrict__ bias,         // [N] or null
    unsigned short* __restrict__ Cb,        // [M][N] bf16 out
    int M, int N, int K, int gx) {
  __shared__ unsigned short As[2][2][128 * 64];
  __shared__ unsigned short Bs[2][2][128 * 64];
  int tid = threadIdx.x, wid = tid >> 6, lane = tid & 63;

  int bid = blockIdx.x, cpx = (int)gridDim.x >> 3;
  int swz = (bid & 7) * cpx + (bid >> 3);
  int m0 = (swz / gx) << 8, n0 = (swz % gx) << 8;

  int wm = (wid >> 2) << 7;   // 0 or 128
  int wn = (wid & 3) << 6;    // 0,64,128,192
  int ha = wm >> 7, hb = wn >> 7, rb = wn & 64;
  int r4 = lane & 15, ksl = lane >> 4;
  int srow = lane >> 3, gs = (lane & 7) ^ srow;  // inverse-swizzled slot

  f4 acc[8][4];
#pragma unroll
  for (int i = 0; i < 8; i++)
#pragma unroll
    for (int j = 0; j < 4; j++) acc[i][j] = (f4){0.f, 0.f, 0.f, 0.f};
  bf8 af[4][2], bfr[4][2];

  auto SA = [&](int h, int t) {  // stage A half h of K-tile t (2 loads/thread)
    int buf = t & 1, k0 = t << 6;
#pragma unroll
    for (int i = 0; i < 2; i++) {
      int ch = wid * 2 + i;  // 1KB chunk = 8 rows x 128B
      gload16(A + (size_t)(m0 + h * 128 + ch * 8 + srow) * K + k0 + gs * 8,
              &As[buf][h][ch * 512]);
    }
  };
  auto SB = [&](int h, int t) {
    int buf = t & 1, k0 = t << 6;
#pragma unroll
    for (int i = 0; i < 2; i++) {
      int ch = wid * 2 + i;
      gload16(Bt + (size_t)(n0 + h * 128 + ch * 8 + srow) * K + k0 + gs * 8,
              &Bs[buf][h][ch * 512]);
    }
  };
  auto LA = [&](int g, int buf) {  // af <- mi-group g (rows g*64..g*64+63)
#pragma unroll
    for (int mi = 0; mi < 4; mi++) {
      int r = g * 64 + mi * 16 + r4;
#pragma unroll
      for (int k2 = 0; k2 < 2; k2++)
        af[mi][k2] = *(const bf8*)((const char*)As[buf][ha] + r * 128 +
                                   ((((k2 << 2) | ksl) ^ (r & 7)) << 4));
    }
  };

  int nt = K >> 6;
  // prologue: FIFO order B0(0),B1(0),A0(0),A1(0),B0(1),B1(1) = 12 loads
  SB(0, 0); SB(1, 0); SA(0, 0); SA(1, 0); SB(0, 1); SB(1, 1);
  wait_vm<4>();  // tile 0 fully landed (newest 4 = B halves of tile 1)
  bar();

  for (int T = 0; T < nt; T++) {
    int buf = T & 1;
    // ---- q0: quadrant (mi0-3, ni0-1)
    LA(0, buf);
    LB256(0, buf);
    if (T + 1 < nt) SA(0, T + 1);
    bar(); lgk0();
    MQ256(0, 0);
    bar();
    // ---- q1: quadrant (mi0-3, ni2-3)
    LB256(1, buf);
    if (T + 1 < nt) SA(1, T + 1);
    bar(); lgk0();
    MQ256(0, 1);
    bar();
    // ---- q2: quadrant (mi4-7, ni0-1)
    LA(1, buf);
    if (T + 2 < nt) SB(0, T + 2);
    bar(); lgk0();
    MQ256(1, 0);
    bar();
    // ---- q3: quadrant (mi4-7, ni2-3)
    if (T + 2 < nt) SB(1, T + 2);
    bar(); lgk0();
    MQ256(1, 1);
    if (T + 1 < nt) {           // ensure tile T+1 landed before its q0 reads
      if (T + 2 < nt) wait_vm<4>();  // newest 4 = B halves of tile T+2
      else            wait_vm<0>();  // no B(T+2) staged: drain
    }
    bar();
  }
  wait_vm<0>();  // drain any stragglers before epilogue/end

  // epilogue: line-major (ni inner -> 4x32B completes each 128B line)
  int rq = ksl << 2;
  float bv[4];
#pragma unroll
  for (int ni = 0; ni < 4; ni++)
    bv[ni] = bias ? bias[n0 + wn + ni * 16 + r4] : 0.0f;
#pragma unroll
  for (int mi = 0; mi < 8; mi++) {
#pragma unroll
    for (int j = 0; j < 4; j++) {
      int row = m0 + wm + mi * 16 + rq + j;
#pragma unroll
      for (int ni = 0; ni < 4; ni++) {
        int col = n0 + wn + ni * 16 + r4;
        float v = acc[mi][ni][j] + bv[ni];
        if (ACT) v = gelu_f(v);
        Cb[(size_t)row * N + col] = f2b(v);
      }
    }
  }
}

// ---------------------------------------------------------------------------
// Small-N bf16 MFMA GEMM (Wo / MLP2): 128x64 tile, BK=32, 4 waves 2x2,
// LINEAR LDS (64B rows; 16-row fragment reads are dense-bijective ->
// conflict-free without swizzle), counted-vmcnt depth-2 (r4/r5-proven loop),
// 4 blocks/CU. Non-swapped MFMA; line-major fp32/bf16 epilogue.
// ---------------------------------------------------------------------------
template <int BM, int BN, int ACT>
__global__ __launch_bounds__(256, 4) void gemm_t(
    const unsigned short* __restrict__ A,   // [M][K] bf16
    const unsigned short* __restrict__ Bt,  // [N][K] bf16
    const float* __restrict__ bias,         // [N] or null
    const float* __restrict__ res,          // [M][N] fp32 or null
    float* __restrict__ Cf,                 // fp32 out (or null)
    unsigned short* __restrict__ Cb,        // bf16 out (or null)
    int M, int N, int K, int gx) {
  constexpr int WM = BM / 2, WN = BN / 2;
  constexpr int FM = WM / 16, FN = WN / 16;
  constexpr int NCHA = BM / 16;            // A 1KB chunks (16 rows x 64B)
  constexpr int NCH = (BM + BN) / 16;
  constexpr int L = NCH / 4;               // chunks (loads) per wave per step
  __shared__ unsigned short As[2][BM * 32];
  __shared__ unsigned short Bs[2][BN * 32];
  int tid = threadIdx.x, wid = tid >> 6, lane = tid & 63;

  int bid = blockIdx.x, cpx = (int)gridDim.x >> 3;
  int swz = (bid & 7) * cpx + (bid >> 3);
  int m0 = (swz / gx) * BM, n0 = (swz % gx) * BN;

  int wm = (wid >> 1) * WM, wn = (wid & 1) * WN;
  int r4 = lane & 15, ksl = lane >> 4;
  int srow = lane >> 2, gs = lane & 3;     // linear: row in chunk, 16B slot

  f4 acc[FM][FN];
#pragma unroll
  for (int i = 0; i < FM; i++)
#pragma unroll
    for (int j = 0; j < FN; j++) acc[i][j] = (f4){0.f, 0.f, 0.f, 0.f};

  auto STAGE = [&](int buf, int t) {
    int k0 = t << 5;
#pragma unroll
    for (int i = 0; i < L; i++) {
      int c = wid * L + i;
      if (c < NCHA)
        gload16(A + (size_t)(m0 + c * 16 + srow) * K + k0 + gs * 8,
                &As[buf][c * 512]);
      else
        gload16(Bt + (size_t)(n0 + (c - NCHA) * 16 + srow) * K + k0 + gs * 8,
                &Bs[buf][(c - NCHA) * 512]);
    }
  };

  auto COMPUTE = [&](int buf) {
    bf8 af[FM], bfr[FN];
#pragma unroll
    for (int mi = 0; mi < FM; mi++)
      af[mi] = *(const bf8*)((const char*)&As[buf][0] +
                             (wm + mi * 16 + r4) * 64 + ksl * 16);
#pragma unroll
    for (int ni = 0; ni < FN; ni++)
      bfr[ni] = *(const bf8*)((const char*)&Bs[buf][0] +
                              (wn + ni * 16 + r4) * 64 + ksl * 16);
    __builtin_amdgcn_s_setprio(1);
#pragma unroll
    for (int mi = 0; mi < FM; mi++)
#pragma unroll
      for (int ni = 0; ni < FN; ni++)
        acc[mi][ni] = __builtin_amdgcn_mfma_f32_16x16x32_bf16(
            af[mi], bfr[ni], acc[mi][ni], 0, 0, 0);
    __builtin_amdgcn_s_setprio(0);
  };

  int nt = K >> 5;
  STAGE(0, 0);
  STAGE(1, 1);
  for (int t = 0; t < nt; t++) {
    if (t + 1 < nt) wait_vm<L>();   // tile t landed; tile t+1 in flight
    else            wait_vm<0>();
    bar();
    COMPUTE(t & 1);
    bar();                          // all waves done reading buf[t&1]
    if (t + 2 < nt) STAGE(t & 1, t + 2);
  }

  // epilogue: ni inner (line-major)
  int rq = ksl << 2;
  float bv[FN];
#pragma unroll
  for (int ni = 0; ni < FN; ni++)
    bv[ni] = bias ? bias[n0 + wn + ni * 16 + r4] : 0.0f;
#pragma unroll
  for (int mi = 0; mi < FM; mi++) {
#pragma unroll
    for (int j = 0; j < 4; j++) {
      int row = m0 + wm + mi * 16 + rq + j;
#pragma unroll
      for (int ni = 0; ni < FN; ni++) {
        int col = n0 + wn + ni * 16 + r4;
        float v = acc[mi][ni][j] + bv[ni];
        if (ACT) v = gelu_f(v);
        if (res) v += res[(size_t)row * N + col];
        if (Cf) Cf[(size_t)row * N + col] = v;
        else    Cb[(size_t)row * N + col] = f2b(v);
      }
    }
  }
}

// ---------------------------------------------------------------------------
// Flash attention, bf16 MFMA. grid (S/64, NH, B), block 256 (4 waves).
// Wave w owns q-rows w*16..w*16+15 of the 64-row Q tile.
// All LDS tiles are 64 rows x 64 bf16 (128B rows, 8 slots), slot^=(row&7).
// ---------------------------------------------------------------------------
__global__ __launch_bounds__(256) void attn_mfma(
    const unsigned short* __restrict__ QKV,  // [B*S][1536]
    const int* __restrict__ vlen,
    unsigned short* __restrict__ AO) {       // [B*S][512]
  __shared__ unsigned short Qs[64 * 64];
  __shared__ unsigned short Ks[64 * 64];
  __shared__ unsigned short Vt[64 * 64];     // transposed: [d][k]
  __shared__ unsigned short Ps[64 * 64];     // [q][k]
  int b = blockIdx.z, h = blockIdx.y, q0 = blockIdx.x << 6;
  int tid = threadIdx.x, wid = tid >> 6, lane = tid & 63;
  int vl = vlen[b];
  int r4 = lane & 15, ksl = lane >> 4;

  // ---- stage Q (2 chunks of 1KB per wave; chunk = 8 rows of 128B)
  int srow = lane >> 3;                 // 0..7
  int gs = (lane & 7) ^ srow;           // inverse-swizzled 16B slot
  {
    const unsigned short* qsrc =
        QKV + (size_t)(b * SS + q0 + wid * 16 + srow) * LDQKV + h * 64 + gs * 8;
    gload16(qsrc, Qs + wid * 1024);
    gload16(qsrc + (size_t)8 * LDQKV, Qs + wid * 1024 + 512);
  }
  const unsigned short* kbase =
      QKV + (size_t)(b * SS + wid * 16 + srow) * LDQKV + DD + h * 64 + gs * 8;
  int vp = tid & 31, vdg = (tid >> 5) << 3;
  const unsigned short* vbase =
      QKV + (size_t)(b * SS + 2 * vp) * LDQKV + 2 * DD + h * 64 + vdg;

  f4 o[4];
#pragma unroll
  for (int i = 0; i < 4; i++) o[i] = (f4){0.f, 0.f, 0.f, 0.f};
  float mrun[4], lrun[4];
#pragma unroll
  for (int j = 0; j < 4; j++) { mrun[j] = -3e38f; lrun[j] = 0.0f; }

  int ntiles = (vl + 63) >> 6;
  if (ntiles > 16) ntiles = 16;

  for (int t = 0; t < ntiles; t++) {
    int kg0 = t << 6;
    // stage K via global_load_lds
    const unsigned short* ks = kbase + (size_t)kg0 * LDQKV;
    gload16(ks, Ks + wid * 1024);
    gload16(ks + (size_t)8 * LDQKV, Ks + wid * 1024 + 512);
    // stage V transposed: pack key-pairs into u32, swizzled ds_write_b32
    {
      const unsigned short* v0 = vbase + (size_t)kg0 * LDQKV;
      const unsigned short* v1 = v0 + LDQKV;
      unsigned short va[8], vb[8];
      *(uint4*)va = *(const uint4*)v0;
      *(uint4*)vb = *(const uint4*)v1;
#pragma unroll
      for (int i = 0; i < 8; i++) {
        int d = vdg + i;
        unsigned val = (unsigned)va[i] | ((unsigned)vb[i] << 16);
        int byte = (d << 7) + (((vp >> 2) ^ (d & 7)) << 4) + ((vp & 3) << 2);
        *(unsigned*)((char*)Vt + byte) = val;
      }
    }
    __syncthreads();

    // ---- S = Q @ K^T  (rows: this wave's 16 q; cols: 64 keys)
    f4 s[4];
#pragma unroll
    for (int i = 0; i < 4; i++) s[i] = (f4){0.f, 0.f, 0.f, 0.f};
#pragma unroll
    for (int k2 = 0; k2 < 2; k2++) {
      int slot = (k2 << 2) + ksl;
      int qr = (wid << 4) + r4;
      bf8 aq = *(const bf8*)((const char*)Qs + (qr << 7) + ((slot ^ (qr & 7)) << 4));
#pragma unroll
      for (int ni = 0; ni < 4; ni++) {
        int kr = (ni << 4) + r4;
        bf8 bk = *(const bf8*)((const char*)Ks + (kr << 7) + ((slot ^ (kr & 7)) << 4));
        s[ni] = __builtin_amdgcn_mfma_f32_16x16x32_bf16(aq, bk, s[ni], 0, 0, 0);
      }
    }

    // ---- online softmax (rows in-register; 16-lane shfl reduce)
#pragma unroll
    for (int j = 0; j < 4; j++) {
      int qr = (wid << 4) + ((lane >> 4) << 2) + j;
      float sv[4], mx = -3e38f;
#pragma unroll
      for (int ni = 0; ni < 4; ni++) {
        float v = s[ni][j] * 0.125f;                       // 1/sqrt(64)
        if (kg0 + (ni << 4) + r4 >= vl) v = -1e6f;         // masked_softmax
        sv[ni] = v;
        mx = fmaxf(mx, v);
      }
#pragma unroll
      for (int m2 = 1; m2 < 16; m2 <<= 1) mx = fmaxf(mx, __shfl_xor(mx, m2));
      float mnew = fmaxf(mrun[j], mx);
      float al = __expf(mrun[j] - mnew);
      float ls = 0.0f;
      unsigned short pb[4];
#pragma unroll
      for (int ni = 0; ni < 4; ni++) {
        float p = __expf(sv[ni] - mnew);
        ls += p;
        pb[ni] = f2b(p);
      }
#pragma unroll
      for (int m2 = 1; m2 < 16; m2 <<= 1) ls += __shfl_xor(ls, m2);
      lrun[j] = lrun[j] * al + ls;
      mrun[j] = mnew;
#pragma unroll
      for (int ni = 0; ni < 4; ni++) {
        int kc = (ni << 4) + r4;
        int byte = (qr << 7) + (((kc >> 3) ^ (qr & 7)) << 4) + ((kc & 7) << 1);
        *(unsigned short*)((char*)Ps + byte) = pb[ni];
        o[ni][j] *= al;
      }
    }

    // ---- O += P @ V   (A = P rows of this wave; B cols = d via Vt)
#pragma unroll
    for (int k2 = 0; k2 < 2; k2++) {
      int slot = (k2 << 2) + ksl;
      int qr = (wid << 4) + r4;
      bf8 ap = *(const bf8*)((const char*)Ps + (qr << 7) + ((slot ^ (qr & 7)) << 4));
#pragma unroll
      for (int ni = 0; ni < 4; ni++) {
        int dr = (ni << 4) + r4;
        bf8 bv = *(const bf8*)((const char*)Vt + (dr << 7) + ((slot ^ (dr & 7)) << 4));
        o[ni] = __builtin_amdgcn_mfma_f32_16x16x32_bf16(ap, bv, o[ni], 0, 0, 0);
      }
    }
    __syncthreads();  // before next tile overwrites Ks/Vt
  }

  float inv[4];
#pragma unroll
  for (int j = 0; j < 4; j++) inv[j] = 1.0f / lrun[j];
#pragma unroll
  for (int ni = 0; ni < 4; ni++) {
#pragma unroll
    for (int j = 0; j < 4; j++) {
      int qr = (wid << 4) + ((lane >> 4) << 2) + j;
      int d = (ni << 4) + r4;
      AO[(size_t)(b * SS + q0 + qr) * DD + h * 64 + d] = f2b(o[ni][j] * inv[j]);
    }
  }
}

// ---------------------------------------------------------------------------
extern "C" void kernel_launch(void* const* d_in, const int* in_sizes, int n_in,
                              void* d_out, int out_size, void* d_ws,
                              size_t ws_size, hipStream_t stream) {
  const float* X    = (const float*)d_in[0];
  const int*   vln  = (const int*)d_in[1];
  const float* ln1g = (const float*)d_in[2];
  const float* ln1b = (const float*)d_in[3];
  const float* Wq   = (const float*)d_in[4];
  const float* Wk   = (const float*)d_in[5];
  const float* Wv   = (const float*)d_in[6];
  const float* Wo   = (const float*)d_in[7];
  const float* ln2g = (const float*)d_in[8];
  const float* ln2b = (const float*)d_in[9];
  const float* W1   = (const float*)d_in[10];
  const float* b1   = (const float*)d_in[11];
  const float* W2   = (const float*)d_in[12];
  const float* b2   = (const float*)d_in[13];
  float* out = (float*)d_out;

  unsigned short* ws = (unsigned short*)d_ws;
  unsigned short* h     = ws;                          // 8192x512
  unsigned short* QKVb  = h     + (size_t)MM * DD;     // 8192x1536
  unsigned short* AOb   = QKVb  + (size_t)MM * LDQKV;  // 8192x512
  unsigned short* mid   = AOb   + (size_t)MM * DD;     // 8192x2048
  unsigned short* Wqkvt = mid   + (size_t)MM * FF;     // 1536x512
  unsigned short* Wot   = Wqkvt + (size_t)3 * DD * DD; // 512x512
  unsigned short* W1t   = Wot   + (size_t)DD * DD;     // 2048x512
  unsigned short* W2t   = W1t   + (size_t)FF * DD;     // 512x2048

  dim3 blk(256);
  dim3 blk8(512);

  // weight prep: transpose + convert to bf16 [N][K]
  tconv4<<<dim3(16, 16, 4), blk, 0, stream>>>(
      Wq, Wk, Wv, Wo, Wqkvt, Wqkvt + (size_t)DD * DD,
      Wqkvt + (size_t)2 * DD * DD, Wot);
  tconv<<<dim3(64, 16), blk, 0, stream>>>(W1, W1t, DD, FF);
  tconv<<<dim3(16, 64), blk, 0, stream>>>(W2, W2t, FF, DD);

  // 1. h = bf16(LN1(X))
  ln_bf16<<<dim3(MM / 4), blk, 0, stream>>>(X, ln1g, ln1b, h);
  // 2. QKV = h @ [Wq|Wk|Wv]  (bf16 out)  [8-phase 256x256, 192 blocks]
  gemm256<0><<<dim3((LDQKV / 256) * (MM / 256)), blk8, 0, stream>>>(
      h, Wqkvt, nullptr, QKVb, MM, LDQKV, DD, LDQKV / 256);
  // 3. attention
  attn_mfma<<<dim3(SS / 64, NH, BB), blk, 0, stream>>>(QKVb, vln, AOb);
  // 4. out = X + AO @ Wo   (fp32)  [128x64, 512 blocks, 4/CU]
  gemm_t<128, 64, 0><<<dim3((DD / 64) * (MM / 128)), blk, 0, stream>>>(
      AOb, Wot, nullptr, X, out, nullptr, MM, DD, DD, DD / 64);
  // 5. h2 = bf16(LN2(out))  (overlays h)
  ln_bf16<<<dim3(MM / 4), blk, 0, stream>>>(out, ln2g, ln2b, h);
  // 6. mid = bf16(gelu(h2 @ W1 + b1))  [8-phase 256x256, 256 blocks]
  gemm256<1><<<dim3((FF / 256) * (MM / 256)), blk8, 0, stream>>>(
      h, W1t, b1, mid, MM, FF, DD, FF / 256);
  // 7. out = out + mid @ W2 + b2  (fp32, in-place residual)  [128x64, 512 blk]
  gemm_t<128, 64, 0><<<dim3((DD / 64) * (MM / 128)), blk, 0, stream>>>(
      mid, W2t, b2, out, out, nullptr, MM, DD, FF, DD / 64);
}